// Round 1
// 404.999 us; speedup vs baseline: 1.0068x; 1.0068x over previous
//
#include <hip/hip_runtime.h>

// DynamicMultiRNN: 2-layer shared-weight LSTM, B=1024 T=200 D=128, residual on L2.
// f32 I/O, bf16 MFMA internals.
//
// R6 = R5 + three latency-chain fixes:
//  (1) __syncthreads() -> {s_waitcnt lgkmcnt(0); s_barrier} raw pair.
//      __syncthreads emits s_waitcnt vmcnt(0) expcnt(0) lgkmcnt(0) before
//      s_barrier, which drained the 4 per-iter global out-stores (never read
//      back) and the x-prefetch (already consumed) on the critical path of
//      all 201 barriers. Only lgkmcnt(0) is required for LDS visibility.
//  (2) exp2 scale constants folded into pre-scaled bf16 weight fragments +
//      bias; bias preloaded into the MFMA accumulator (saves ~8 VALU ops per
//      gate-cell: 16 adds + 12 muls + 16 movs per wave-iter).
//  (3) h1n cross-half __shfl_xor moved off the pre-barrier tail to the top of
//      the NEXT iteration (hsave registers persist across the barrier; value
//      not needed until the gate phase).
// Plus: all 8 ds_read_b128 A-fragments hoisted ahead of the MFMA chain
// (VGPR headroom is free at 8 waves/CU), s_setprio(1) around MFMAs (T5).
//
// PACKED A-TILE (unchanged): both layers share [W;U], one 16x256 tile holds
// rows 0-7  = [x(i)     | h1(i-1)]  (layer-1 inputs, 8 batch rows)
// rows 8-15 = [h1n(i-1) | h2(i-2)]  (layer-2 inputs, same 8 batch rows)
// One GEMM -> z1 and z2 together: 32 MFMAs/wave/iter. 128 blocks x 512 thr.
// Lanes 0-31 do L1 gates (carry c1), lanes 32-63 do L2 gates (carry c2).
// Double-buffered LDS + single barrier/iter; 1-step software pipeline
// (iter i computes L1@i and L2@(i-1)); 201 iterations.
// RS=264 kept: row stride must be ==0 mod 8 elems for ds_read_b128 alignment;
// read pattern is at the 8-lane/bank-group floor, write conflicts ~1%.

typedef __bf16 bf16_t;
typedef __bf16 bf16x8 __attribute__((ext_vector_type(8)));
typedef float f32x4 __attribute__((ext_vector_type(4)));

#define B_ 1024
#define T_ 200
#define D_ 128
#define G_ 512            // 4*D
#define RS 264            // A-tile row stride, bf16 elems: 256 cols + 8 pad (528 B)

__device__ __forceinline__ unsigned int pack2_bf16(float2 f) {
    union { bf16_t h[2]; unsigned int u; } cv;
    cv.h[0] = (bf16_t)f.x; cv.h[1] = (bf16_t)f.y;
    return cv.u;
}

__global__ __launch_bounds__(512, 2)
void lstm2_kernel(const float* __restrict__ x,
                  const float* __restrict__ W,
                  const float* __restrict__ U,
                  const float* __restrict__ bias,
                  float* __restrict__ out)
{
    __shared__ __align__(16) bf16_t A[2][16 * RS];   // double-buffered packed tile

    const int tid  = threadIdx.x;
    const int w    = tid >> 6;           // wave 0..7
    const int lane = tid & 63;
    const int lo   = lane & 15;
    const int quad = lane >> 4;
    const bool isL2 = (lane >= 32);      // quads 2,3 -> A-rows 8..15 (layer 2)
    const int r0   = blockIdx.x * 8;     // 8 batch rows per block

    // zero both buffers (h1(-1)=h2(-2)=h2(-1)=0; everything finite)
    {
        unsigned int* a32 = (unsigned int*)&A[0][0];
        for (int i = tid; i < 2 * 16 * RS / 2; i += 512) a32[i] = 0u;
    }

    // ---- weight fragments (f32 -> bf16 regs), loaded once, reused 201x ----
    // B-frag mfma_f32_16x16x32_bf16: lane holds B[k][n], n = 16*ct + lo,
    // k = 32*kt + quad*8 + jj. k<128 -> W row k, else U row k-128.
    // Wave w's col-tiles ct = w + 8*c (c = gate i,f,g,o).
    // Weights pre-scaled by the gate's exp2 constant:
    //   sig(z)  = rcp(1 + exp2(-log2e   * z))  -> scale -1.4427 (gates i,f,o)
    //   tanh(z) = 2*rcp(1 + exp2(-2log2e* z))-1 -> scale -2.8854 (gate g)
    bf16x8 Breg[8][4];
    #pragma unroll
    for (int kt = 0; kt < 8; ++kt) {
        const int k0 = kt * 32 + quad * 8;
        #pragma unroll
        for (int c = 0; c < 4; ++c) {
            const float gs = (c == 2) ? -2.88539008177792681472f : -1.44269504088896340736f;
            const int n = (w + 8 * c) * 16 + lo;
            const float* src = (k0 < 128) ? (W + (size_t)k0 * G_ + n)
                                          : (U + (size_t)(k0 - 128) * G_ + n);
            bf16x8 v;
            #pragma unroll
            for (int jj = 0; jj < 8; ++jj) v[jj] = (bf16_t)(src[(size_t)jj * G_] * gs);
            Breg[kt][c] = v;
        }
    }

    // lane's gate column j; pre-scaled biases i,f,g,o preloaded into acc init
    const int j = w * 16 + lo;
    f32x4 binit[4];
    #pragma unroll
    for (int c = 0; c < 4; ++c) {
        const float gs = (c == 2) ? -2.88539008177792681472f : -1.44269504088896340736f;
        const float bs = bias[j + 128 * c] * gs;
        binit[c] = (f32x4){bs, bs, bs, bs};
    }

    // x staging: 512 threads x float2 -> 2 bf16; row = tid/64 (0..7), col = (tid%64)*2
    const int xrow = tid >> 6;
    const int xcol = (tid & 63) * 2;
    const size_t xbase = (size_t)(r0 + xrow) * T_ * D_ + xcol;

    // stage x(0) into buffer 0, rows 0-7 cols 0-127
    *reinterpret_cast<unsigned int*>(&A[0][xrow * RS + xcol]) =
        pack2_bf16(*reinterpret_cast<const float2*>(x + xbase));

    float cst[4]   = {0.f, 0.f, 0.f, 0.f};   // c1 (lanes<32) or c2 (lanes>=32)
    float hsave[4] = {0.f, 0.f, 0.f, 0.f};   // previous iter's hnew (persists across barrier)
    float h1prev[4];                          // L2 lanes: h1n(i-1) f32, via shfl

    const int fo = lo * RS + quad * 8;        // A-fragment base offset

    for (int i = 0; i <= T_; ++i) {
        // ---- barrier WITHOUT vmcnt/expcnt drain ----
        // lgkmcnt(0): own ds_writes (and shfl/ds ops) complete -> visible in LDS.
        // s_barrier: all waves arrived => all writes visible. Global stores
        // (out) and the x-prefetch are intentionally NOT drained here.
        asm volatile("s_waitcnt lgkmcnt(0)" ::: "memory");
        __builtin_amdgcn_s_barrier();
        asm volatile("" ::: "memory");            // no memory op hoists above the barrier
        __builtin_amdgcn_sched_barrier(0);        // MIR-level pin

        const int pb = i & 1;
        const int nb = pb ^ 1;

        // h1n(i-1): cross-half exchange of last iter's hnew (off the barrier tail;
        // overlaps with fragment reads, not needed until the gate phase)
        #pragma unroll
        for (int q = 0; q < 4; ++q)
            h1prev[q] = __shfl_xor(hsave[q], 32, 64);

        // global prefetch x(i+1)
        float2 xv;
        const bool do_x = (i + 1 < T_);
        if (do_x)
            xv = *reinterpret_cast<const float2*>(x + xbase + (size_t)(i + 1) * D_);

        // ---- 8 fragment loads up front, then one packed GEMM ----
        bf16x8 af[8];
        #pragma unroll
        for (int kt = 0; kt < 8; ++kt)
            af[kt] = *reinterpret_cast<const bf16x8*>(&A[pb][fo + kt * 32]);

        f32x4 acc[4];
        #pragma unroll
        for (int c = 0; c < 4; ++c) acc[c] = binit[c];   // bias pre-loaded (scaled)

        __builtin_amdgcn_s_setprio(1);
        #pragma unroll
        for (int kt = 0; kt < 8; ++kt) {
            #pragma unroll
            for (int c = 0; c < 4; ++c)
                acc[c] = __builtin_amdgcn_mfma_f32_16x16x32_bf16(af[kt], Breg[kt][c], acc[c], 0, 0, 0);
        }
        __builtin_amdgcn_s_setprio(0);

        // ---- gates; acc is pre-scaled so transcendental inputs are direct ----
        // L1 lanes active for i<T (computing step i); L2 lanes for i>=1 (step i-1)
        const bool upd = isL2 ? (i >= 1) : (i < T_);
        #pragma unroll
        for (int q = 0; q < 4; ++q) {
            float ig = __builtin_amdgcn_rcpf(1.0f + __builtin_amdgcn_exp2f(acc[0][q]));
            float fg = __builtin_amdgcn_rcpf(1.0f + __builtin_amdgcn_exp2f(acc[1][q]));
            float gg = 2.0f * __builtin_amdgcn_rcpf(1.0f + __builtin_amdgcn_exp2f(acc[2][q])) - 1.0f;
            float og = __builtin_amdgcn_rcpf(1.0f + __builtin_amdgcn_exp2f(acc[3][q]));
            float cn = fg * cst[q] + ig * gg;
            float tn = 2.0f * __builtin_amdgcn_rcpf(1.0f +
                         __builtin_amdgcn_exp2f(cn * -2.88539008177792681472f)) - 1.0f;
            float hn = og * tn + (isL2 ? h1prev[q] : 0.0f);
            cst[q]   = upd ? cn : cst[q];
            hsave[q] = upd ? hn : 0.0f;       // 0 keeps LDS clean at edge steps
        }

        // ---- writes to next buffer ----
        // all lanes: own next-state h (L1 rows 0-7 / L2 rows 8-15, cols 128-255)
        #pragma unroll
        for (int q = 0; q < 4; ++q)
            A[nb][(quad * 4 + q) * RS + 128 + j] = (bf16_t)hsave[q];
        // L1 lanes: h1n(i) is also layer-2's next input (rows 8-15, cols 0-127)
        if (!isL2) {
            #pragma unroll
            for (int q = 0; q < 4; ++q)
                A[nb][(8 + quad * 4 + q) * RS + j] = (bf16_t)hsave[q];
        }
        // L2 lanes: emit y(i-1) = h2n (hsave already includes the residual).
        // These global stores are no longer drained at the barrier.
        if (i >= 1 && isL2) {
            #pragma unroll
            for (int q = 0; q < 4; ++q) {
                const int rb = (quad - 2) * 4 + q;   // batch-row within block
                out[(size_t)(r0 + rb) * T_ * D_ + (size_t)(i - 1) * D_ + j] = hsave[q];
            }
        }
        // x(i+1) -> rows 0-7, cols 0-127 (compiler inserts counted vmcnt for xv)
        if (do_x)
            *reinterpret_cast<unsigned int*>(&A[nb][xrow * RS + xcol]) = pack2_bf16(xv);
    }
}

extern "C" void kernel_launch(void* const* d_in, const int* in_sizes, int n_in,
                              void* d_out, int out_size, void* d_ws, size_t ws_size,
                              hipStream_t stream) {
    const float* x = (const float*)d_in[0];
    const float* W = (const float*)d_in[1];
    const float* U = (const float*)d_in[2];
    const float* b = (const float*)d_in[3];
    // d_in[4] = seq_len (int32) — intentionally ignored, matching the reference.
    float* out = (float*)d_out;

    lstm2_kernel<<<dim3(B_ / 8), dim3(512), 0, stream>>>(x, W, U, b, out);
}

// Round 2
// 348.071 us; speedup vs baseline: 1.1714x; 1.1636x over previous
//
#include <hip/hip_runtime.h>

// DynamicMultiRNN: 2-layer shared-weight LSTM, B=1024 T=200 D=128, residual on L2.
// f32 I/O, bf16 MFMA internals.
//
// R7 = R6 restructured for latency, the two big levers:
//  (1) 4 batch rows/block -> 256 blocks: ALL 256 CUs active (was 128, Occ 11.5%).
//      The A-tile's rows 8-15 hold a DUPLICATE of rows 0-7, so the 16x16 MFMA's
//      upper output rows are copies: quads 2,3 pick up batch rows 2,3 via a
//      single v_cndmask select (no shfl). Per-lane gate cells: 4 -> 2, i.e.
//      per-wave transcendentals 40 -> 20 — the dominant VALU issue block halves.
//      MFMA count/wave unchanged (pipe has headroom at 15-30% util).
//  (2) x prefetch held a FULL iteration in registers: load x(i+2) at iter i,
//      store x(i+1) (loaded last iter) right after the barrier. Removes the
//      same-iteration global-load -> LDS-store latency chain from the tail.
// Kept from R6: lgkmcnt-only barrier, pre-scaled weights/bias in accumulator,
// setprio around MFMA, hoisted fragment loads.
//
// PACKED A-TILE (16 x 256, RS=264 stride):
// rows 0-3  = [x_b(i)     | h1_b(i-1)]   L1 inputs, batch rows b=0..3
// rows 4-7  = [h1n_b(i-1) | h2_b(i-2)]   L2 inputs
// rows 8-15 = duplicate of rows 0-7      (fills MFMA M=16)
// One GEMM -> z1 and z2 (+dups): 32 MFMAs/wave/iter, 8 ds_read_b128/lane.
// Cell ownership: quad0 -> L1 b=0,1 | quad1 -> L2 b=0,1 | quad2 -> L1 b=2,3
//                 quad3 -> L2 b=2,3   (2 cells/lane, all lanes useful)
// h1n residual crosses quad0<->quad1, quad2<->quad3 via __shfl_xor(.,16).
// Double-buffered LDS, single barrier/iter, 1-step L1/L2 pipeline, 201 iters.

typedef __bf16 bf16_t;
typedef __bf16 bf16x8 __attribute__((ext_vector_type(8)));
typedef float f32x4 __attribute__((ext_vector_type(4)));

#define B_ 1024
#define T_ 200
#define D_ 128
#define G_ 512            // 4*D
#define RS 264            // A-tile row stride, bf16 elems: 256 cols + 8 pad (528 B)

__device__ __forceinline__ unsigned int pack2_bf16(float2 f) {
    union { bf16_t h[2]; unsigned int u; } cv;
    cv.h[0] = (bf16_t)f.x; cv.h[1] = (bf16_t)f.y;
    return cv.u;
}

__global__ __launch_bounds__(512, 2)
void lstm2_kernel(const float* __restrict__ x,
                  const float* __restrict__ W,
                  const float* __restrict__ U,
                  const float* __restrict__ bias,
                  float* __restrict__ out)
{
    __shared__ __align__(16) bf16_t A[2][16 * RS];   // double-buffered packed tile

    const int tid  = threadIdx.x;
    const int w    = tid >> 6;           // wave 0..7
    const int lane = tid & 63;
    const int lo   = lane & 15;
    const int quad = lane >> 4;
    const bool isL2 = (quad & 1);        // quads 1,3 -> layer 2
    const bool hiB  = (quad >= 2);       // quads 2,3 -> batch rows 2,3 (dup rows)
    const int  qoff = hiB ? 2 : 0;
    const int r0   = blockIdx.x * 4;     // 4 batch rows per block

    // zero both buffers (h1(-1)=h2(-2)=h2(-1)=0; everything finite)
    {
        unsigned int* a32 = (unsigned int*)&A[0][0];
        for (int k = tid; k < 2 * 16 * RS / 2; k += 512) a32[k] = 0u;
    }

    // ---- weight fragments (f32 -> bf16 regs), loaded once, reused 201x ----
    // B-frag mfma_f32_16x16x32_bf16: lane holds B[k][n], n = 16*ct + lo,
    // k = 32*kt + quad*8 + jj. k<128 -> W row k, else U row k-128.
    // Wave w's col-tiles ct = w + 8*c (c = gate i,f,g,o).
    // Weights pre-scaled by the gate's exp2 constant:
    //   sig(z)  = rcp(1 + exp2(-log2e   * z))  -> scale -1.4427 (gates i,f,o)
    //   tanh(z) = 2*rcp(1 + exp2(-2log2e* z))-1 -> scale -2.8854 (gate g)
    bf16x8 Breg[8][4];
    #pragma unroll
    for (int kt = 0; kt < 8; ++kt) {
        const int k0 = kt * 32 + quad * 8;
        #pragma unroll
        for (int c = 0; c < 4; ++c) {
            const float gs = (c == 2) ? -2.88539008177792681472f : -1.44269504088896340736f;
            const int n = (w + 8 * c) * 16 + lo;
            const float* src = (k0 < 128) ? (W + (size_t)k0 * G_ + n)
                                          : (U + (size_t)(k0 - 128) * G_ + n);
            bf16x8 v;
            #pragma unroll
            for (int jj = 0; jj < 8; ++jj) v[jj] = (bf16_t)(src[(size_t)jj * G_] * gs);
            Breg[kt][c] = v;
        }
    }

    // lane's gate column j; pre-scaled biases preloaded into acc init
    const int j = w * 16 + lo;
    f32x4 binit[4];
    #pragma unroll
    for (int c = 0; c < 4; ++c) {
        const float gs = (c == 2) ? -2.88539008177792681472f : -1.44269504088896340736f;
        const float bs = bias[j + 128 * c] * gs;
        binit[c] = (f32x4){bs, bs, bs, bs};
    }

    // x staging: 512 threads x float2; xrow = tid>>6 (0..7):
    //   source batch row = xrow&3; dest A row = rows 0-3 and dup rows 8-11.
    const int xrow = tid >> 6;
    const int xsrc = xrow & 3;
    const int arow = (xrow < 4) ? xrow : (xrow + 4);
    const int xcol = (tid & 63) * 2;
    const size_t xbase = (size_t)(r0 + xsrc) * T_ * D_ + xcol;
    const int xdst = arow * RS + xcol;

    // stage x(0) into buffer 0
    *reinterpret_cast<unsigned int*>(&A[0][xdst]) =
        pack2_bf16(*reinterpret_cast<const float2*>(x + xbase));
    // prefetch x(1) into registers (held one full iteration before LDS store)
    float2 xv_hold = *reinterpret_cast<const float2*>(x + xbase + (size_t)D_);

    float cst[2]   = {0.f, 0.f};   // c1 (L1 lanes) or c2 (L2 lanes), per cell
    float hsave[2] = {0.f, 0.f};   // previous iter's hnew (persists across barrier)
    float h1prev[2];               // L2 lanes: h1n(i-1) f32, via shfl

    const int fo = lo * RS + quad * 8;   // A-fragment base (row = lo, reads dup rows too)

    for (int i = 0; i <= T_; ++i) {
        // ---- barrier WITHOUT vmcnt/expcnt drain (lgkmcnt only) ----
        asm volatile("s_waitcnt lgkmcnt(0)" ::: "memory");
        __builtin_amdgcn_s_barrier();
        asm volatile("" ::: "memory");
        __builtin_amdgcn_sched_barrier(0);

        const int pb = i & 1;
        const int nb = pb ^ 1;

        // x(i+1) -> next buffer, value loaded LAST iteration (latency fully hidden);
        // safe: A[nb] was fully read by iter i-1, barrier above closed those reads.
        if (i + 1 < T_)
            *reinterpret_cast<unsigned int*>(&A[nb][xdst]) = pack2_bf16(xv_hold);
        // issue load of x(i+2), held until next iteration
        if (i + 2 < T_)
            xv_hold = *reinterpret_cast<const float2*>(x + xbase + (size_t)(i + 2) * D_);

        // h1n(i-1): L1 quad -> L2 quad partner (lane ^ 16)
        h1prev[0] = __shfl_xor(hsave[0], 16, 64);
        h1prev[1] = __shfl_xor(hsave[1], 16, 64);

        // ---- 8 fragment loads up front, then one packed GEMM ----
        bf16x8 af[8];
        #pragma unroll
        for (int kt = 0; kt < 8; ++kt)
            af[kt] = *reinterpret_cast<const bf16x8*>(&A[pb][fo + kt * 32]);

        f32x4 acc[4];
        #pragma unroll
        for (int c = 0; c < 4; ++c) acc[c] = binit[c];   // bias pre-loaded (scaled)

        __builtin_amdgcn_s_setprio(1);
        #pragma unroll
        for (int kt = 0; kt < 8; ++kt) {
            #pragma unroll
            for (int c = 0; c < 4; ++c)
                acc[c] = __builtin_amdgcn_mfma_f32_16x16x32_bf16(af[kt], Breg[kt][c], acc[c], 0, 0, 0);
        }
        __builtin_amdgcn_s_setprio(0);

        // ---- gates: 2 cells/lane; acc rows 8-15 are dups, so hiB lanes
        // select q+2 (one v_cndmask per value, no cross-lane traffic) ----
        // L1 lanes active for i<T (step i); L2 lanes for i>=1 (step i-1)
        const bool upd = isL2 ? (i >= 1) : (i < T_);
        #pragma unroll
        for (int q = 0; q < 2; ++q) {
            float z0 = hiB ? acc[0][q + 2] : acc[0][q];
            float z1 = hiB ? acc[1][q + 2] : acc[1][q];
            float z2 = hiB ? acc[2][q + 2] : acc[2][q];
            float z3 = hiB ? acc[3][q + 2] : acc[3][q];
            float ig = __builtin_amdgcn_rcpf(1.0f + __builtin_amdgcn_exp2f(z0));
            float fg = __builtin_amdgcn_rcpf(1.0f + __builtin_amdgcn_exp2f(z1));
            float gg = 2.0f * __builtin_amdgcn_rcpf(1.0f + __builtin_amdgcn_exp2f(z2)) - 1.0f;
            float og = __builtin_amdgcn_rcpf(1.0f + __builtin_amdgcn_exp2f(z3));
            float cn = fg * cst[q] + ig * gg;
            float tn = 2.0f * __builtin_amdgcn_rcpf(1.0f +
                         __builtin_amdgcn_exp2f(cn * -2.88539008177792681472f)) - 1.0f;
            float hn = og * tn + (isL2 ? h1prev[q] : 0.0f);
            cst[q]   = upd ? cn : cst[q];
            hsave[q] = upd ? hn : 0.0f;   // 0 keeps LDS clean at edge steps
        }

        // ---- writes to next buffer (primary + dup rows) ----
        #pragma unroll
        for (int q = 0; q < 2; ++q) {
            const int b = qoff + q;              // batch row 0..3
            const bf16_t hb = (bf16_t)hsave[q];
            if (!isL2) {
                // h1n(b): L1 recurrent input (rows b, 8+b; cols 128-255)
                //         and L2 next input  (rows 4+b, 12+b; cols 0-127)
                A[nb][b * RS + 128 + j]        = hb;
                A[nb][(8 + b) * RS + 128 + j]  = hb;
                A[nb][(4 + b) * RS + j]        = hb;
                A[nb][(12 + b) * RS + j]       = hb;
            } else {
                // h2n(b): L2 recurrent input (rows 4+b, 12+b; cols 128-255)
                A[nb][(4 + b) * RS + 128 + j]  = hb;
                A[nb][(12 + b) * RS + 128 + j] = hb;
            }
        }

        // L2 lanes: emit y(i-1) = h2n (hsave includes the residual);
        // global stores are never drained at the barrier.
        if (i >= 1 && isL2) {
            #pragma unroll
            for (int q = 0; q < 2; ++q)
                out[(size_t)(r0 + qoff + q) * T_ * D_ + (size_t)(i - 1) * D_ + j] = hsave[q];
        }
    }
}

extern "C" void kernel_launch(void* const* d_in, const int* in_sizes, int n_in,
                              void* d_out, int out_size, void* d_ws, size_t ws_size,
                              hipStream_t stream) {
    const float* x = (const float*)d_in[0];
    const float* W = (const float*)d_in[1];
    const float* U = (const float*)d_in[2];
    const float* b = (const float*)d_in[3];
    // d_in[4] = seq_len (int32) — intentionally ignored, matching the reference.
    float* out = (float*)d_out;

    lstm2_kernel<<<dim3(B_ / 4), dim3(512), 0, stream>>>(x, W, U, b, out);
}

// Round 3
// 327.504 us; speedup vs baseline: 1.2450x; 1.0628x over previous
//
#include <hip/hip_runtime.h>

// DynamicMultiRNN: 2-layer shared-weight LSTM, B=1024 T=200 D=128, residual on L2.
// f32 I/O, bf16 MFMA internals.
//
// R8 = R7 with dup rows ELIMINATED from LDS (dup-at-read):
//  The A-tile stores only 8 distinct rows; the MFMA A-fragment reads row
//  (lo & 7), so lanes 8-15 broadcast-read rows 0-7 and the MFMA's output
//  rows 8-15 are duplicates exactly as before — acc layout unchanged.
//  Effects (bank map: row r, col c -> bank (4r + c/2) mod 32; rows r and r+8
//  aliased, which is what made R7's dup-row stores 2x the conflicts):
//   - LDS writes halve: L1 2 stores/cell (was 4), L2 1 (was 2); x staged once.
//   - Every store instr now lands its 4 active quads on disjoint 8-bank
//     octets (rows {q,2+q,4+q,6+q} -> offsets {4q,8+4q,16+4q,24+4q}) -> ~0
//     write conflicts.
//   - A-fragment reads: lo / lo+8 same address -> HW broadcast, read cycles halve.
//  Plus: out[] pointers hoisted out of the loop; x staged as 1 f32/thread.
// Kept from R7: 4 batch rows/block (256 blocks, all CUs), packed L1+L2 tile,
// lgkmcnt-only barrier, pre-scaled weights/bias-in-accumulator, setprio,
// hoisted fragment loads, x prefetch held a full iteration in registers.
//
// PACKED A-TILE (8 x 256, RS=264 stride):
// rows 0-3 = [x_b(i)     | h1_b(i-1)]   L1 inputs, batch rows b=0..3
// rows 4-7 = [h1n_b(i-1) | h2_b(i-2)]   L2 inputs
// One GEMM -> z1 and z2 (+dup output rows): 32 MFMAs/wave/iter.
// Cell ownership: quad0 -> L1 b=0,1 | quad1 -> L2 b=0,1 | quad2 -> L1 b=2,3
//                 quad3 -> L2 b=2,3   (2 cells/lane; hiB lanes select acc q+2)
// h1n residual crosses quad0<->quad1, quad2<->quad3 via __shfl_xor(.,16).
// Double-buffered LDS, single barrier/iter, 1-step L1/L2 pipeline, 201 iters.

typedef __bf16 bf16_t;
typedef __bf16 bf16x8 __attribute__((ext_vector_type(8)));
typedef float f32x4 __attribute__((ext_vector_type(4)));

#define B_ 1024
#define T_ 200
#define D_ 128
#define G_ 512            // 4*D
#define RS 264            // A-tile row stride, bf16 elems: 256 cols + 8 pad (528 B)

__global__ __launch_bounds__(512, 2)
void lstm2_kernel(const float* __restrict__ x,
                  const float* __restrict__ W,
                  const float* __restrict__ U,
                  const float* __restrict__ bias,
                  float* __restrict__ out)
{
    __shared__ __align__(16) bf16_t A[2][8 * RS];    // double-buffered packed tile

    const int tid  = threadIdx.x;
    const int w    = tid >> 6;           // wave 0..7
    const int lane = tid & 63;
    const int lo   = lane & 15;
    const int quad = lane >> 4;
    const bool isL2 = (quad & 1);        // quads 1,3 -> layer 2
    const bool hiB  = (quad >= 2);       // quads 2,3 -> batch rows 2,3 (dup acc rows)
    const int  qoff = hiB ? 2 : 0;
    const int r0   = blockIdx.x * 4;     // 4 batch rows per block

    // zero both buffers (h1(-1)=h2(-2)=h2(-1)=0; everything finite)
    {
        unsigned int* a32 = (unsigned int*)&A[0][0];
        for (int k = tid; k < 2 * 8 * RS / 2; k += 512) a32[k] = 0u;
    }

    // ---- weight fragments (f32 -> bf16 regs), loaded once, reused 201x ----
    // B-frag mfma_f32_16x16x32_bf16: lane holds B[k][n], n = 16*ct + lo,
    // k = 32*kt + quad*8 + jj. k<128 -> W row k, else U row k-128.
    // Wave w's col-tiles ct = w + 8*c (c = gate i,f,g,o).
    // Weights pre-scaled by the gate's exp2 constant:
    //   sig(z)  = rcp(1 + exp2(-log2e   * z))  -> scale -1.4427 (gates i,f,o)
    //   tanh(z) = 2*rcp(1 + exp2(-2log2e* z))-1 -> scale -2.8854 (gate g)
    bf16x8 Breg[8][4];
    #pragma unroll
    for (int kt = 0; kt < 8; ++kt) {
        const int k0 = kt * 32 + quad * 8;
        #pragma unroll
        for (int c = 0; c < 4; ++c) {
            const float gs = (c == 2) ? -2.88539008177792681472f : -1.44269504088896340736f;
            const int n = (w + 8 * c) * 16 + lo;
            const float* src = (k0 < 128) ? (W + (size_t)k0 * G_ + n)
                                          : (U + (size_t)(k0 - 128) * G_ + n);
            bf16x8 v;
            #pragma unroll
            for (int jj = 0; jj < 8; ++jj) v[jj] = (bf16_t)(src[(size_t)jj * G_] * gs);
            Breg[kt][c] = v;
        }
    }

    // lane's gate column j; pre-scaled biases preloaded into acc init
    const int j = w * 16 + lo;
    f32x4 binit[4];
    #pragma unroll
    for (int c = 0; c < 4; ++c) {
        const float gs = (c == 2) ? -2.88539008177792681472f : -1.44269504088896340736f;
        const float bs = bias[j + 128 * c] * gs;
        binit[c] = (f32x4){bs, bs, bs, bs};
    }

    // x staging: 512 threads x 1 f32 -> 1 bf16; row = tid>>7 (0..3), col = tid&127
    const int xrow = tid >> 7;
    const int xcol = tid & 127;
    const size_t xbase = (size_t)(r0 + xrow) * T_ * D_ + xcol;
    const int xdst = xrow * RS + xcol;

    // stage x(0) into buffer 0; prefetch x(1) into a register (held one iter)
    A[0][xdst] = (bf16_t)x[xbase];
    float xv_hold = x[xbase + (size_t)D_];

    float cst[2]   = {0.f, 0.f};   // c1 (L1 lanes) or c2 (L2 lanes), per cell
    float hsave[2] = {0.f, 0.f};   // previous iter's hnew (persists across barrier)
    float h1prev[2];               // L2 lanes: h1n(i-1) f32, via shfl

    // A-fragment base: row (lo&7) -> lanes 8-15 broadcast-read rows 0-7
    const int fo = (lo & 7) * RS + quad * 8;

    // out pointers hoisted (used by L2 lanes only; cells q=0,1 -> rows qoff+q)
    float* outp0 = out + (size_t)(r0 + qoff + 0) * T_ * D_ + j;
    float* outp1 = out + (size_t)(r0 + qoff + 1) * T_ * D_ + j;

    for (int i = 0; i <= T_; ++i) {
        // ---- barrier WITHOUT vmcnt/expcnt drain (lgkmcnt only) ----
        asm volatile("s_waitcnt lgkmcnt(0)" ::: "memory");
        __builtin_amdgcn_s_barrier();
        asm volatile("" ::: "memory");
        __builtin_amdgcn_sched_barrier(0);

        const int pb = i & 1;
        const int nb = pb ^ 1;

        // x(i+1) -> next buffer, value loaded LAST iteration (latency hidden);
        // safe: A[nb] was fully read by iter i-1, barrier above closed those reads.
        if (i + 1 < T_)
            A[nb][xdst] = (bf16_t)xv_hold;
        // issue load of x(i+2), held until next iteration
        if (i + 2 < T_)
            xv_hold = x[xbase + (size_t)(i + 2) * D_];

        // h1n(i-1): L1 quad -> L2 quad partner (lane ^ 16)
        h1prev[0] = __shfl_xor(hsave[0], 16, 64);
        h1prev[1] = __shfl_xor(hsave[1], 16, 64);

        // ---- 8 fragment loads up front, then one packed GEMM ----
        bf16x8 af[8];
        #pragma unroll
        for (int kt = 0; kt < 8; ++kt)
            af[kt] = *reinterpret_cast<const bf16x8*>(&A[pb][fo + kt * 32]);

        f32x4 acc[4];
        #pragma unroll
        for (int c = 0; c < 4; ++c) acc[c] = binit[c];   // bias pre-loaded (scaled)

        __builtin_amdgcn_s_setprio(1);
        #pragma unroll
        for (int kt = 0; kt < 8; ++kt) {
            #pragma unroll
            for (int c = 0; c < 4; ++c)
                acc[c] = __builtin_amdgcn_mfma_f32_16x16x32_bf16(af[kt], Breg[kt][c], acc[c], 0, 0, 0);
        }
        __builtin_amdgcn_s_setprio(0);

        // ---- gates: 2 cells/lane; acc rows 8-15 are read-time dups, so hiB
        // lanes select q+2 (one v_cndmask per value, no cross-lane traffic) ----
        // L1 lanes active for i<T (step i); L2 lanes for i>=1 (step i-1)
        const bool upd = isL2 ? (i >= 1) : (i < T_);
        #pragma unroll
        for (int q = 0; q < 2; ++q) {
            float z0 = hiB ? acc[0][q + 2] : acc[0][q];
            float z1 = hiB ? acc[1][q + 2] : acc[1][q];
            float z2 = hiB ? acc[2][q + 2] : acc[2][q];
            float z3 = hiB ? acc[3][q + 2] : acc[3][q];
            float ig = __builtin_amdgcn_rcpf(1.0f + __builtin_amdgcn_exp2f(z0));
            float fg = __builtin_amdgcn_rcpf(1.0f + __builtin_amdgcn_exp2f(z1));
            float gg = 2.0f * __builtin_amdgcn_rcpf(1.0f + __builtin_amdgcn_exp2f(z2)) - 1.0f;
            float og = __builtin_amdgcn_rcpf(1.0f + __builtin_amdgcn_exp2f(z3));
            float cn = fg * cst[q] + ig * gg;
            float tn = 2.0f * __builtin_amdgcn_rcpf(1.0f +
                         __builtin_amdgcn_exp2f(cn * -2.88539008177792681472f)) - 1.0f;
            float hn = og * tn + (isL2 ? h1prev[q] : 0.0f);
            cst[q]   = upd ? cn : cst[q];
            hsave[q] = upd ? hn : 0.0f;   // 0 keeps LDS clean at edge steps
        }

        // ---- writes to next buffer (primary rows only — no dups) ----
        // Bank check: per store instr the 4 active quads hit rows {q,2+q,4+q,6+q}
        // or {4+q,6+q} -> disjoint 8-bank octets -> conflict-free.
        #pragma unroll
        for (int q = 0; q < 2; ++q) {
            const int b = qoff + q;              // batch row 0..3
            const bf16_t hb = (bf16_t)hsave[q];
            if (!isL2) {
                // h1n(b): L1 recurrent input (row b, cols 128-255)
                //         and L2 next input  (row 4+b, cols 0-127)
                A[nb][b * RS + 128 + j]       = hb;
                A[nb][(4 + b) * RS + j]       = hb;
            } else {
                // h2n(b): L2 recurrent input (row 4+b, cols 128-255)
                A[nb][(4 + b) * RS + 128 + j] = hb;
            }
        }

        // L2 lanes: emit y(i-1) = h2n (hsave includes the residual);
        // global stores are never drained at the barrier.
        if (i >= 1 && isL2) {
            outp0[(size_t)(i - 1) * D_] = hsave[0];
            outp1[(size_t)(i - 1) * D_] = hsave[1];
        }
    }
}

extern "C" void kernel_launch(void* const* d_in, const int* in_sizes, int n_in,
                              void* d_out, int out_size, void* d_ws, size_t ws_size,
                              hipStream_t stream) {
    const float* x = (const float*)d_in[0];
    const float* W = (const float*)d_in[1];
    const float* U = (const float*)d_in[2];
    const float* b = (const float*)d_in[3];
    // d_in[4] = seq_len (int32) — intentionally ignored, matching the reference.
    float* out = (float*)d_out;

    lstm2_kernel<<<dim3(B_ / 4), dim3(512), 0, stream>>>(x, W, U, b, out);
}